// Round 4
// baseline (25.499 us; speedup 1.0000x reference)
//
#include <hip/hip_runtime.h>

// Rate-1/2, K=7 non-recursive conv encoder, B x 4096 -> B x 8192.
// out0[t] = m[t]^m[t-2]^m[t-3]^m[t-5]^m[t-6]   (G1 = 1011011)
// out1[t] = m[t]^m[t-1]^m[t-2]^m[t-3]^m[t-6]   (G2 = 1111001)
// cw[b, 2t] = out0[t], cw[b, 2t+1] = out1[t]
//
// R4 = R3 with the nontemporal store done through a native clang vector type
// (ext_vector_type), since __builtin_nontemporal_store rejects HIP_vector_type.

#define K_BITS 4096
#define F4_PER_ROW (K_BITS / 2)   // 2048 output float4s per row
#define UNROLL 4

typedef float floatx4 __attribute__((ext_vector_type(4)));

__device__ __forceinline__ unsigned bit_of(float v) {
    // v is exactly 0.0f or 1.0f -> exponent-bit0 (0x3F800000) is the value.
    return (__float_as_uint(v) >> 23) & 1u;
}

__global__ __launch_bounds__(256) void conv_encode_kernel(
        const float* __restrict__ in, float* __restrict__ out, int total_f4) {
    const int stride = gridDim.x * 256;
    const int f4_0   = blockIdx.x * 256 + threadIdx.x;

    floatx4 a[UNROLL], b[UNROLL];
    unsigned w[UNROLL];

    // Phase 1: issue all loads (independent chunks -> deep MLP).
#pragma unroll
    for (int u = 0; u < UNROLL; ++u) {
        const int f4  = f4_0 + u * stride;
        const int row = f4 >> 11;            // /2048
        const int idx = f4 & 2047;
        const int t0  = idx << 1;
        const float* p = in + (size_t)row * K_BITS;
        if (idx >= 3) {
            a[u] = *reinterpret_cast<const floatx4*>(p + t0 - 6);
            b[u] = *reinterpret_cast<const floatx4*>(p + t0 - 2);
            w[u] = 0xffffffffu;              // marker: fast path
        } else {
            unsigned ww = 0;
#pragma unroll
            for (int k = 0; k < 8; ++k) {
                const int t = t0 - 6 + k;
                if (t >= 0) ww |= bit_of(p[t]) << k;
            }
            w[u] = ww;                       // (never 0xffffffff: bits 8+ clear)
        }
    }

    // Phase 2: pack, encode, store (dense 64x16B per instruction).
#pragma unroll
    for (int u = 0; u < UNROLL; ++u) {
        unsigned ww;
        if (w[u] == 0xffffffffu) {
            ww =  bit_of(a[u].x)
               | (bit_of(a[u].y) << 1)
               | (bit_of(a[u].z) << 2)
               | (bit_of(a[u].w) << 3)
               | (bit_of(b[u].x) << 4)
               | (bit_of(b[u].y) << 5)
               | (bit_of(b[u].z) << 6)
               | (bit_of(b[u].w) << 7);
        } else {
            ww = w[u];
        }

        const unsigned y0 = (ww >> 6) ^ (ww >> 4) ^ (ww >> 3) ^ (ww >> 1) ^ ww;
        const unsigned y1 = (ww >> 6) ^ (ww >> 5) ^ (ww >> 4) ^ (ww >> 3) ^ ww;

        floatx4 o;
        o.x = (float)( y0       & 1u);
        o.y = (float)( y1       & 1u);
        o.z = (float)((y0 >> 1) & 1u);
        o.w = (float)((y1 >> 1) & 1u);

        const int f4 = f4_0 + u * stride;
        __builtin_nontemporal_store(
            o, reinterpret_cast<floatx4*>(out + (size_t)f4 * 4));
    }
}

extern "C" void kernel_launch(void* const* d_in, const int* in_sizes, int n_in,
                              void* d_out, int out_size, void* d_ws, size_t ws_size,
                              hipStream_t stream) {
    const float* in = (const float*)d_in[0];   // [B, 4096] of 0.0/1.0
    float* out = (float*)d_out;                // [B, 8192]

    const int B = in_sizes[0] / K_BITS;        // 2048
    const int total_f4 = B * F4_PER_ROW;       // 4.19M output float4s
    const int threads = total_f4 / UNROLL;     // exact: B*2048 % 4 == 0
    const int blocks = threads / 256;

    conv_encode_kernel<<<blocks, 256, 0, stream>>>(in, out, total_f4);
}